// Round 14
// baseline (33.431 us; speedup 1.0000x reference)
//
#include <hip/hip_runtime.h>
#include <hip/hip_fp16.h>

typedef _Float16 f16x8 __attribute__((ext_vector_type(8)));
typedef float f32x4 __attribute__((ext_vector_type(4)));

#define N_PTS 32768
#define ROWS 64         // rows per block

// ---- prep: repack W2 (fp32 [4096][64]) + b2 into f16 fragments for
// 16x16x32 MFMA (R6-proven layout). 130 blocks: c = bid>>1, half u = bid&1.
//   wsB[c*4096 + t*8 + j], t = q*64+lane: frag q = s*4+nt holds
//   Wf[c*64 + s*32 + ((lane>>4)&3)*8 + j][nt*16 + (lane&15)]
__global__ __launch_bounds__(256) void prep_kernel(
    const float* __restrict__ W2, const float* __restrict__ b2,
    _Float16* __restrict__ wsB) {
  __shared__ _Float16 w_lds[64][72];
  const int c   = blockIdx.x >> 1;
  const int u   = blockIdx.x & 1;
  const int tid = threadIdx.x;
  {  // coalesced: 16 consecutive f32 -> f16 -> LDS (whole chunk)
    const float* src = (c < 64) ? (W2 + c * 4096 + tid * 16) : (b2 + tid * 16);
    int kl = tid >> 2, o = (tid & 3) * 16;
    f16x8 v0, v1;
    #pragma unroll
    for (int j = 0; j < 8; ++j) {
      v0[j] = (_Float16)src[j];
      v1[j] = (_Float16)src[8 + j];
    }
    *(f16x8*)(&w_lds[kl][o])     = v0;
    *(f16x8*)(&w_lds[kl][o + 8]) = v1;
  }
  __syncthreads();
  {
    int t = tid + u * 256;           // dest frag-slot within c: 0..511
    int q = t >> 6, lane = t & 63;
    int klbase = (q >> 2) * 32 + ((lane >> 4) & 3) * 8;
    int o      = (q & 3) * 16 + (lane & 15);
    f16x8 v;
    #pragma unroll
    for (int j = 0; j < 8; ++j) v[j] = w_lds[klbase + j][o];
    *(f16x8*)(wsB + c * 4096 + t * 8) = v;
  }
}

// ---- main: N-split waves, no reduce, 4 waves/SIMD ----
// 512 blocks x 512 threads (8 waves = 2 mg x 4 nt), 64 rows/block, 2/CU.
// Wave (mg,nt): rows [32mg,+32) x cols [16nt,+16), ALL 65 chunks -> acc[2]
// final, direct store. Per chunk: 2 b128 B-loads (3-slot rotation), 2 h-reads
// (LDS scalar), 16 pk_mul, 4 MFMA. Fully static 65-deep unroll.
__global__ __launch_bounds__(512) void main_kernel(
    const float* __restrict__ x, const float* __restrict__ gridp,
    const float* __restrict__ W1, const float* __restrict__ b1,
    const _Float16* __restrict__ wsB, float* __restrict__ out) {

  __shared__ _Float16 h_lds[ROWS][72];   // 9216 B
  __shared__ _Float16 x_lds[ROWS][72];   // 9216 B ; total 18432 -> 2 blocks/CU

  const int tid  = threadIdx.x;
  const int lane = tid & 63;
  const int wave = tid >> 6;
  const int mg   = wave >> 2;        // row half: rows [32mg, 32mg+32)
  const int nt   = wave & 3;         // col quarter: cols [16nt, 16nt+16)
  const int rowblk = blockIdx.x * ROWS;
  const int mrow = lane & 15;        // A row within 16-tile / D col
  const int kgrp = lane >> 4;        // 0..3

  // phase 0+1: x tile + h, one row-octave per thread (row = tid>>3, 8 k's)
  {
    int row = tid >> 3;
    int ko  = (tid & 7) * 8;
    int r = rowblk + row;
    // x: 8 consecutive f32 -> f16
    const float* xp = x + r * 64 + ko;
    f32x4 xa = *(const f32x4*)(xp);
    f32x4 xb = *(const f32x4*)(xp + 4);
    float g0 = gridp[r * 3 + 0], g1 = gridp[r * 3 + 1], g2 = gridp[r * 3 + 2];
    f16x8 xv, hv;
    #pragma unroll
    for (int j = 0; j < 4; ++j) {
      xv[j]     = (_Float16)xa[j];
      xv[4 + j] = (_Float16)xb[j];
    }
    #pragma unroll
    for (int q = 0; q < 8; ++q) {
      int k = ko + q;
      float v = g0 * W1[k] + g1 * W1[64 + k] + g2 * W1[128 + k] + b1[k];
      float v2 = v * v;
      float u  = v * fmaf(0.044715f, v2, 1.0f);
      float e  = exp2f(u * 2.3022084f);     // e^{1.59577*u} in log2
      float rr = e + 1.0f;
      float inv;
      asm("v_rcp_f32 %0, %1" : "=v"(inv) : "v"(rr));
      hv[q] = (_Float16)(v * (1.0f - inv)); // tanh-gelu
    }
    *(f16x8*)(&x_lds[row][ko]) = xv;
    *(f16x8*)(&h_lds[row][ko]) = hv;
  }
  __syncthreads();

  // x fragments: xf[m][s] = x_lds[32mg + m*16 + mrow][s*32 + kgrp*8 ..+8]
  f16x8 xf[2][2];
  #pragma unroll
  for (int m = 0; m < 2; ++m)
    #pragma unroll
    for (int s = 0; s < 2; ++s)
      xf[m][s] = *(const f16x8*)(&x_lds[mg * 32 + m * 16 + mrow][s * 32 + kgrp * 8]);

  f32x4 acc[2];
  acc[0] = (f32x4){0.f, 0.f, 0.f, 0.f};
  acc[1] = (f32x4){0.f, 0.f, 0.f, 0.f};

  const _Float16* bp = wsB + lane * 8;
  f16x8 bf[3][2];                    // 3-slot rotation, 2 frags (s=0,1) each
  auto LOADB = [&](int slot, int c) {
    bf[slot][0] = *(const f16x8*)(bp + (c * 8 + nt) * 512);
    bf[slot][1] = *(const f16x8*)(bp + (c * 8 + 4 + nt) * 512);
  };

  LOADB(0, 0);
  LOADB(1, 1);
  LOADB(2, 2);

  // K-loop: 64 scaled chunks + bias chunk 64 (h == 1). All indices static.
  #pragma unroll
  for (int p = 0; p < 65; ++p) {
    const int slot = p % 3;
    if (p < 64) {
      #pragma unroll
      for (int m = 0; m < 2; ++m) {
        _Float16 hh = h_lds[mg * 32 + m * 16 + mrow][p];
        f16x8 hs = {hh, hh, hh, hh, hh, hh, hh, hh};
        acc[m] = __builtin_amdgcn_mfma_f32_16x16x32_f16(xf[m][0] * hs, bf[slot][0], acc[m], 0, 0, 0);
        acc[m] = __builtin_amdgcn_mfma_f32_16x16x32_f16(xf[m][1] * hs, bf[slot][1], acc[m], 0, 0, 0);
      }
    } else {   // bias: A = xf directly
      #pragma unroll
      for (int m = 0; m < 2; ++m) {
        acc[m] = __builtin_amdgcn_mfma_f32_16x16x32_f16(xf[m][0], bf[slot][0], acc[m], 0, 0, 0);
        acc[m] = __builtin_amdgcn_mfma_f32_16x16x32_f16(xf[m][1], bf[slot][1], acc[m], 0, 0, 0);
      }
    }
    if (p + 3 < 65) LOADB(slot, p + 3);
  }

  // epilogue: direct store. row = 32mg + m*16 + kgrp*4 + r, col = 16nt + mrow
  #pragma unroll
  for (int m = 0; m < 2; ++m) {
    int row = rowblk + mg * 32 + m * 16 + kgrp * 4;
    #pragma unroll
    for (int r = 0; r < 4; ++r)
      out[(row + r) * 64 + nt * 16 + mrow] = acc[m][r];
  }
}

extern "C" void kernel_launch(void* const* d_in, const int* in_sizes, int n_in,
                              void* d_out, int out_size, void* d_ws, size_t ws_size,
                              hipStream_t stream) {
  const float* x    = (const float*)d_in[0];
  const float* grid = (const float*)d_in[1];
  const float* W1   = (const float*)d_in[2];
  const float* b1   = (const float*)d_in[3];
  const float* W2   = (const float*)d_in[4];
  const float* b2   = (const float*)d_in[5];
  float* out = (float*)d_out;
  _Float16* wsB = (_Float16*)d_ws;   // 65*4096*2 = 532480 bytes

  hipLaunchKernelGGL(prep_kernel, dim3(130), dim3(256), 0, stream,
                     W2, b2, wsB);
  hipLaunchKernelGGL(main_kernel, dim3(N_PTS / ROWS), dim3(512), 0, stream,
                     x, grid, W1, b1, wsB, out);
}

// Round 15
// 31.995 us; speedup vs baseline: 1.0449x; 1.0449x over previous
//
#include <hip/hip_runtime.h>
#include <hip/hip_fp16.h>

typedef _Float16 f16x8 __attribute__((ext_vector_type(8)));
typedef float f32x4 __attribute__((ext_vector_type(4)));

#define N_PTS 32768
#define ROWS 64         // rows per block
#define X_STRIDE 72     // f16; 144 B rows: 16B-aligned b128, reads 2-way max
#define P_STRIDE 68     // f32; 272 B rows: 16B-aligned

// ---- prep: repack W2 + b2 into f16 MFMA fragment layout (proven R6 version)
__global__ __launch_bounds__(256) void prep_kernel(
    const float* __restrict__ W2, const float* __restrict__ b2,
    _Float16* __restrict__ wsB) {
  __shared__ _Float16 w_lds[64][X_STRIDE];
  const int c   = blockIdx.x;
  const int tid = threadIdx.x;
  {
    const float* src = (c < 64) ? (W2 + c * 4096 + tid * 16) : (b2 + tid * 16);
    int kl = tid >> 2, o = (tid & 3) * 16;
    f16x8 v0, v1;
    #pragma unroll
    for (int j = 0; j < 8; ++j) {
      v0[j] = (_Float16)src[j];
      v1[j] = (_Float16)src[8 + j];
    }
    *(f16x8*)(&w_lds[kl][o])     = v0;
    *(f16x8*)(&w_lds[kl][o + 8]) = v1;
  }
  __syncthreads();
  #pragma unroll
  for (int u = 0; u < 2; ++u) {
    int t = tid + u * 256;
    int q = t >> 6, lane = t & 63;
    int klbase = (q >> 2) * 32 + ((lane >> 4) & 3) * 8;
    int o      = (q & 3) * 16 + (lane & 15);
    f16x8 v;
    #pragma unroll
    for (int j = 0; j < 8; ++j) v[j] = w_lds[klbase + j][o];
    *(f16x8*)(wsB + c * 4096 + t * 8) = v;
  }
}

// ---- main: R12 structure (best: 30.3) + T5 s_setprio around MFMA bursts ----
// 512 blocks x 256 threads (4 waves), 2 blocks/CU. Waves K-split 65 chunks
// (wave w: c = w + 4i; wave 0 also bias c = 64); NO barriers in the K-loop ->
// waves run phase-shifted (the independent-wave regime where setprio pays).
// Triple-buffered register B; h in registers (compile-time extraction).
__global__ __launch_bounds__(256) void main_kernel(
    const float* __restrict__ x, const float* __restrict__ gridp,
    const float* __restrict__ W1, const float* __restrict__ b1,
    const _Float16* __restrict__ wsB, float* __restrict__ out) {

  __shared__ _Float16 h_t[4][ROWS][16];        // 8192 B: h_t[w][row][i] = h[row][w+4i]
  __shared__ float part[4][ROWS * P_STRIDE];   // 69632 B; total 77824 -> 2/CU
  _Float16* x_lds = (_Float16*)&part[0][0];    // [64][X_STRIDE]; dead before part

  const int tid  = threadIdx.x;
  const int lane = tid & 63;
  const int wave = tid >> 6;
  const int rowblk = blockIdx.x * ROWS;

  // phase 0: issue coalesced x-tile load (16 consecutive f32 per thread)
  const float* xsrc = x + rowblk * 64 + tid * 16;
  f32x4 xr0 = *(const f32x4*)(xsrc);
  f32x4 xr1 = *(const f32x4*)(xsrc + 4);
  f32x4 xr2 = *(const f32x4*)(xsrc + 8);
  f32x4 xr3 = *(const f32x4*)(xsrc + 12);

  // phase 1: h = gelu(grid@W1+b1), tanh-form via v_exp (absmax slack 3.7x).
  // Thread (row = tid>>2, w4 = tid&3): k = w4 + 4q -> h_t[w4][row][q].
  {
    int row = tid >> 2;
    int w4  = tid & 3;
    int r = rowblk + row;
    float g0 = gridp[r * 3 + 0], g1 = gridp[r * 3 + 1], g2 = gridp[r * 3 + 2];
    f16x8 h0, h1;
    #pragma unroll
    for (int q = 0; q < 16; ++q) {
      int k = w4 + 4 * q;
      float v = g0 * W1[k] + g1 * W1[64 + k] + g2 * W1[128 + k] + b1[k];
      float v2 = v * v;
      float u  = v * fmaf(0.044715f, v2, 1.0f);
      float e  = __builtin_amdgcn_exp2f(u * 2.3022084f);  // e^{1.59577u}
      float rr = e + 1.0f;
      float inv;
      asm("v_rcp_f32 %0, %1" : "=v"(inv) : "v"(rr));
      float h = v * (1.0f - inv);          // 0.5v(1+tanh(.)) == v(1-1/(e+1))
      if (q < 8) h0[q] = (_Float16)h; else h1[q - 8] = (_Float16)h;
    }
    *(f16x8*)(&h_t[w4][row][0]) = h0;
    *(f16x8*)(&h_t[w4][row][8]) = h1;
  }

  // phase 2: x -> f16 -> LDS (coalesced-in, b128 LDS writes)
  {
    int row = tid >> 2, o = (tid & 3) * 16;
    f16x8 v0, v1;
    #pragma unroll
    for (int j = 0; j < 4; ++j) {
      v0[j]     = (_Float16)xr0[j];
      v0[4 + j] = (_Float16)xr1[j];
      v1[j]     = (_Float16)xr2[j];
      v1[4 + j] = (_Float16)xr3[j];
    }
    *(f16x8*)(&x_lds[row * X_STRIDE + o])     = v0;
    *(f16x8*)(&x_lds[row * X_STRIDE + o + 8]) = v1;
  }
  __syncthreads();

  const int mrow = lane & 15;        // A row within 16-tile / D col
  const int kgrp = lane >> 4;        // 0..3
  const _Float16* bp = wsB + lane * 8;

  auto LOADB = [&](f16x8* b, int c) {
    #pragma unroll
    for (int q = 0; q < 8; ++q)
      b[q] = *(const f16x8*)(bp + (c * 8 + q) * 512);
  };

  // issue first B batches before LDS reads (overlap global latency)
  f16x8 bA[8], bB[8], bC[8];
  LOADB(bA, wave);
  LOADB(bB, wave + 4);
  LOADB(bC, wave + 8);

  // h rows -> registers: hreg[m][half] covers chunk positions 0..15
  f16x8 hreg[4][2];
  #pragma unroll
  for (int m = 0; m < 4; ++m) {
    hreg[m][0] = *(const f16x8*)(&h_t[wave][m * 16 + mrow][0]);
    hreg[m][1] = *(const f16x8*)(&h_t[wave][m * 16 + mrow][8]);
  }

  // x fragments from LDS
  f16x8 xf[4][2];
  #pragma unroll
  for (int m = 0; m < 4; ++m)
    #pragma unroll
    for (int s = 0; s < 2; ++s)
      xf[m][s] = *(const f16x8*)(&x_lds[(m * 16 + mrow) * X_STRIDE + s * 32 + kgrp * 8]);

  f32x4 acc[4][4];
  #pragma unroll
  for (int m = 0; m < 4; ++m)
    #pragma unroll
    for (int n = 0; n < 4; ++n)
      acc[m][n] = (f32x4){0.f, 0.f, 0.f, 0.f};

  // COMPUTE for chunk position p (static after unroll), T5-wrapped: the wave
  // holds elevated priority through its pk_mul+MFMA burst, so load-phase
  // waves on the same SIMD don't steal issue slots mid-burst.
  auto COMPUTE = [&](const f16x8* b, int p) {
    __builtin_amdgcn_s_setprio(1);
    #pragma unroll
    for (int m = 0; m < 4; ++m) {
      _Float16 hh = hreg[m][p >> 3][p & 7];   // compile-time extraction
      f16x8 hs = {hh, hh, hh, hh, hh, hh, hh, hh};
      f16x8 a0 = xf[m][0] * hs;
      f16x8 a1 = xf[m][1] * hs;
      #pragma unroll
      for (int n = 0; n < 4; ++n) {
        acc[m][n] = __builtin_amdgcn_mfma_f32_16x16x32_f16(a0, b[n],     acc[m][n], 0, 0, 0);
        acc[m][n] = __builtin_amdgcn_mfma_f32_16x16x32_f16(a1, b[4 + n], acc[m][n], 0, 0, 0);
      }
    }
    __builtin_amdgcn_s_setprio(0);
  };
  auto COMPUTE_BIAS = [&](const f16x8* b) {   // h == 1: A-frag = xf directly
    __builtin_amdgcn_s_setprio(1);
    #pragma unroll
    for (int m = 0; m < 4; ++m)
      #pragma unroll
      for (int n = 0; n < 4; ++n) {
        acc[m][n] = __builtin_amdgcn_mfma_f32_16x16x32_f16(xf[m][0], b[n],     acc[m][n], 0, 0, 0);
        acc[m][n] = __builtin_amdgcn_mfma_f32_16x16x32_f16(xf[m][1], b[4 + n], acc[m][n], 0, 0, 0);
      }
    __builtin_amdgcn_s_setprio(0);
  };

  // K-loop: positions p = 0..15 (c = wave + 4p), 3-buffer rotation, static.
  #pragma unroll
  for (int g = 0; g < 5; ++g) {
    COMPUTE(bA, 3 * g);
    if (3 * g + 3 < 16) LOADB(bA, wave + 4 * (3 * g + 3));
    COMPUTE(bB, 3 * g + 1);
    if (3 * g + 4 < 16) LOADB(bB, wave + 4 * (3 * g + 4));
    else if (wave == 0) LOADB(bB, 64);       // bias-chunk B, issued early
    COMPUTE(bC, 3 * g + 2);
    if (3 * g + 5 < 16) LOADB(bC, wave + 4 * (3 * g + 5));
  }
  COMPUTE(bA, 15);
  if (wave == 0) COMPUTE_BIAS(bB);

  __syncthreads();   // K-loop done everywhere; x_lds dead -> part writable

  // one-stage reduce: every wave writes its partial buffer...
  {
    float* pw = part[wave];
    #pragma unroll
    for (int m = 0; m < 4; ++m)
      #pragma unroll
      for (int n = 0; n < 4; ++n)
        #pragma unroll
        for (int r = 0; r < 4; ++r)
          pw[(m * 16 + kgrp * 4 + r) * P_STRIDE + n * 16 + mrow] = acc[m][n][r];
  }
  __syncthreads();

  // ...then all 256 threads sum 4 buffers and store (4 threads/row, 16 cols)
  {
    int row = tid >> 2;
    int cb  = (tid & 3) * 16;
    const float* p0 = part[0] + row * P_STRIDE + cb;
    float* op = out + (rowblk + row) * 64 + cb;
    #pragma unroll
    for (int j = 0; j < 4; ++j) {
      f32x4 s = *(const f32x4*)(p0 + j * 4);
      #pragma unroll
      for (int w = 1; w < 4; ++w)
        s += *(const f32x4*)(p0 + w * (ROWS * P_STRIDE) + j * 4);
      *(f32x4*)(op + j * 4) = s;
    }
  }
}

extern "C" void kernel_launch(void* const* d_in, const int* in_sizes, int n_in,
                              void* d_out, int out_size, void* d_ws, size_t ws_size,
                              hipStream_t stream) {
  const float* x    = (const float*)d_in[0];
  const float* grid = (const float*)d_in[1];
  const float* W1   = (const float*)d_in[2];
  const float* b1   = (const float*)d_in[3];
  const float* W2   = (const float*)d_in[4];
  const float* b2   = (const float*)d_in[5];
  float* out = (float*)d_out;
  _Float16* wsB = (_Float16*)d_ws;   // 65*4096*2 = 532480 bytes

  hipLaunchKernelGGL(prep_kernel, dim3(65), dim3(256), 0, stream,
                     W2, b2, wsB);
  hipLaunchKernelGGL(main_kernel, dim3(N_PTS / ROWS), dim3(256), 0, stream,
                     x, grid, W1, b1, wsB, out);
}